// Round 13
// baseline (759.524 us; speedup 1.0000x reference)
//
#include <hip/hip_runtime.h>
#include <hip/hip_bf16.h>

typedef __attribute__((ext_vector_type(8))) short short8;
typedef __attribute__((ext_vector_type(8))) _Float16 half8;
typedef __attribute__((ext_vector_type(4))) _Float16 half4v;
typedef __attribute__((ext_vector_type(4))) float f32x4;
typedef __attribute__((ext_vector_type(16))) float f32x16;
typedef unsigned short us;

#define GLDS16(G, L) __builtin_amdgcn_global_load_lds( \
    (const __attribute__((address_space(1))) void*)(G), \
    (__attribute__((address_space(3))) void*)(L), 16, 0, 0)

__global__ void k_sentinel(float* p) {
    if (threadIdx.x == 0 && blockIdx.x == 0) p[0] = 12345.0f;
}

// fast exact-GELU: Abramowitz-Stegun 7.1.26 erf (max abs err 1.5e-7) + __expf
__device__ __forceinline__ float fast_gelu(float x) {
    float ax = fabsf(x) * 0.70710678118654752f;      // |x|/sqrt(2)
    float t = __frcp_rn(fmaf(0.3275911f, ax, 1.0f));
    float p = fmaf(1.061405429f, t, -1.453152027f);
    p = fmaf(p, t, 1.421413741f);
    p = fmaf(p, t, -0.284496736f);
    p = fmaf(p, t, 0.254829592f);
    p = p * t * __expf(-ax * ax);                    // 1 - erf(|z|)
    float erfv = __builtin_copysignf(1.0f - p, x);
    return 0.5f * x * (1.0f + erfv);
}

// ---------------- cast fp32 -> fp16 ----------------
__global__ void k_cast(const float* __restrict__ in, _Float16* __restrict__ out, long n4) {
    long i = (long)blockIdx.x * blockDim.x + threadIdx.x;
    long stride = (long)gridDim.x * blockDim.x;
    for (; i < n4; i += stride) {
        float4 v = ((const float4*)in)[i];
        half4v h;
        h[0] = (_Float16)v.x; h[1] = (_Float16)v.y;
        h[2] = (_Float16)v.z; h[3] = (_Float16)v.w;
        ((half4v*)out)[i] = h;
    }
}

// ---------------- weight transpose+cast: f32 [K][N] -> fp16 [N][K] ----------------
__global__ void k_wtransh(const float* __restrict__ in, _Float16* __restrict__ out,
                          int K, int N) {
    __shared__ float tile[32][33];
    int n0 = blockIdx.x * 32, k0 = blockIdx.y * 32;
    int tx = threadIdx.x, ty = threadIdx.y;
#pragma unroll
    for (int r = ty; r < 32; r += 8)
        tile[r][tx] = in[(size_t)(k0 + r) * N + n0 + tx];
    __syncthreads();
#pragma unroll
    for (int r = ty; r < 32; r += 8)
        out[(size_t)(n0 + r) * K + k0 + tx] = (_Float16)tile[tx][r];
}

// ---------------- row softmax: 2048 fp32 -> 2048 fp16, one block per row ----------------
__device__ __forceinline__ float wredmax(float v) {
#pragma unroll
    for (int off = 32; off > 0; off >>= 1) v = fmaxf(v, __shfl_xor(v, off, 64));
    return v;
}
__device__ __forceinline__ float wredsum(float v) {
#pragma unroll
    for (int off = 32; off > 0; off >>= 1) v += __shfl_xor(v, off, 64);
    return v;
}

__global__ __launch_bounds__(256) void k_softmax(const float* __restrict__ S,
                                                 _Float16* __restrict__ P) {
    __shared__ float red[8];
    size_t base = (size_t)blockIdx.x * 2048;
    int t = threadIdx.x;
    float4 a = ((const float4*)(S + base))[2 * t];
    float4 b = ((const float4*)(S + base))[2 * t + 1];
    float v[8] = {a.x, a.y, a.z, a.w, b.x, b.y, b.z, b.w};
    float m = v[0];
#pragma unroll
    for (int j = 1; j < 8; j++) m = fmaxf(m, v[j]);
    m = wredmax(m);
    int wv = t >> 6;
    if ((t & 63) == 0) red[wv] = m;
    __syncthreads();
    m = fmaxf(fmaxf(red[0], red[1]), fmaxf(red[2], red[3]));
    float s = 0.f;
#pragma unroll
    for (int j = 0; j < 8; j++) { v[j] = __expf(v[j] - m); s += v[j]; }
    s = wredsum(s);
    if ((t & 63) == 0) red[4 + wv] = s;
    __syncthreads();
    s = red[4] + red[5] + red[6] + red[7];
    float inv = 1.f / s;
    half4v o0, o1;
#pragma unroll
    for (int j = 0; j < 4; j++) o0[j] = (_Float16)(v[j] * inv);
#pragma unroll
    for (int j = 0; j < 4; j++) o1[j] = (_Float16)(v[4 + j] * inv);
    ((half4v*)(P + base))[2 * t] = o0;
    ((half4v*)(P + base))[2 * t + 1] = o1;
}

// ---------------- 128-tile fp16 GEMM, BK=64 single-buffer (round-8 winner) ----------------
// OUT_MODE: 0=f32  4=fp16  5=fp16 transposed per 2048-row batch
template <int OUT_MODE, bool GELU_ACT>
__global__ __launch_bounds__(256, 2) void k_gemm64(
    const us* __restrict__ A, const us* __restrict__ B,
    const float* __restrict__ bias, void* __restrict__ C,
    int N, int K, long sA, long sB, long sC) {
    __shared__ __align__(16) us ldsA[8192];
    __shared__ __align__(16) us ldsB[8192];

    const int tid = threadIdx.x;
    const int wave = tid >> 6, lane = tid & 63;
    const int wr = wave >> 1, wc = wave & 1;
    const int l15 = lane & 15, l4 = lane >> 4;
    const int m0 = blockIdx.x * 128, n0 = blockIdx.y * 128;

    const us* pA = A + (size_t)blockIdx.z * sA;
    const us* pB = B + (size_t)blockIdx.z * sB;
    const size_t zC = (size_t)blockIdx.z * sC;

    f32x4 acc[4][4] = {};

    auto stage = [&](const us* __restrict__ g, us* l, int r0, int kk) {
#pragma unroll
        for (int i = 0; i < 4; i++) {
            int s = (i << 8) + tid;            // 16B slot 0..1023
            int row = s >> 3;                  // 0..127
            int cl = (s & 7) ^ (row & 7);      // pre-swizzled source chunk
            const us* src = g + (size_t)(r0 + row) * K + kk + (cl << 3);
            us* dst = l + (((i << 8) + (wave << 6)) << 3);  // wave-uniform base
            GLDS16(src, dst);
        }
    };

    for (int kk = 0; kk < K; kk += 64) {
        stage(pA, ldsA, m0, kk);
        stage(pB, ldsB, n0, kk);
        __syncthreads();

#pragma unroll
        for (int ks = 0; ks < 2; ks++) {
            short8 af[4], bf[4];
#pragma unroll
            for (int f = 0; f < 4; f++) {
                int ra = (wr << 6) + (f << 4) + l15;
                af[f] = *(const short8*)(
                    &ldsA[(ra << 6) + ((((ks << 2) | l4) ^ (ra & 7)) << 3)]);
                int rb = (wc << 6) + (f << 4) + l15;
                bf[f] = *(const short8*)(
                    &ldsB[(rb << 6) + ((((ks << 2) | l4) ^ (rb & 7)) << 3)]);
            }
#pragma unroll
            for (int fm = 0; fm < 4; fm++)
#pragma unroll
                for (int fn = 0; fn < 4; fn++)
                    acc[fm][fn] = __builtin_amdgcn_mfma_f32_16x16x32_f16(
                        __builtin_bit_cast(half8, af[fm]), __builtin_bit_cast(half8, bf[fn]),
                        acc[fm][fn], 0, 0, 0);
        }
        __syncthreads();
    }

    float bv[4];
#pragma unroll
    for (int fn = 0; fn < 4; fn++)
        bv[fn] = bias ? bias[n0 + (wc << 6) + (fn << 4) + l15] : 0.f;

#pragma unroll
    for (int fm = 0; fm < 4; fm++) {
        int rbase = m0 + (wr << 6) + (fm << 4) + (l4 << 2);
#pragma unroll
        for (int fn = 0; fn < 4; fn++) {
            int col = n0 + (wc << 6) + (fn << 4) + l15;
#pragma unroll
            for (int r = 0; r < 4; r++) {
                float x = acc[fm][fn][r] + bv[fn];
                if (GELU_ACT) x = fast_gelu(x);
                size_t row = (size_t)(rbase + r);
                if (OUT_MODE == 5) {
                    size_t o = ((row >> 11) * (size_t)N + (size_t)col) * 2048 + (row & 2047);
                    ((_Float16*)C)[o] = (_Float16)x;
                } else {
                    size_t o = zC + row * N + col;
                    if (OUT_MODE == 0) ((float*)C)[o] = x;
                    else               ((_Float16*)C)[o] = (_Float16)x;
                }
            }
        }
    }
}

// ---------------- 128-tile fp16 GEMM, BK=64, 32x32x16 MFMA (A/B on MLP) ----------------
// Same staging/swizzle/barriers as k_gemm64; inner loop uses
// mfma_f32_32x32x16_f16: HALF the MFMA instruction count (16 vs 32 per K-tile,
// same 16 ds_read_b128) — targets the issue-saturation (MfmaUtil 41 + VALUBusy
// 60 ≈ 100%). A/B frag: lane -> (row=l&31, k=(l>>5)*8+e), 16B contiguous =
// chunk (ks*2 + l5) ^ (row&7) of the existing layout. C/D: col=lane&31,
// row=(reg&3)+8*(reg>>2)+4*(lane>>5) [m74/m101]. 4 independent accs (ILP ok).
// OUT_MODE: 0=f32  4=fp16
template <int OUT_MODE, bool GELU_ACT>
__global__ __launch_bounds__(256, 2) void k_gemm32(
    const us* __restrict__ A, const us* __restrict__ B,
    const float* __restrict__ bias, void* __restrict__ C,
    int N, int K, long sA, long sB, long sC) {
    __shared__ __align__(16) us ldsA[8192];
    __shared__ __align__(16) us ldsB[8192];

    const int tid = threadIdx.x;
    const int wave = tid >> 6, lane = tid & 63;
    const int wr = wave >> 1, wc = wave & 1;
    const int l31 = lane & 31, l5 = lane >> 5;
    const int m0 = blockIdx.x * 128, n0 = blockIdx.y * 128;

    const us* pA = A + (size_t)blockIdx.z * sA;
    const us* pB = B + (size_t)blockIdx.z * sB;
    const size_t zC = (size_t)blockIdx.z * sC;

    f32x16 acc[2][2] = {};

    auto stage = [&](const us* __restrict__ g, us* l, int r0, int kk) {
#pragma unroll
        for (int i = 0; i < 4; i++) {
            int s = (i << 8) + tid;
            int row = s >> 3;
            int cl = (s & 7) ^ (row & 7);
            const us* src = g + (size_t)(r0 + row) * K + kk + (cl << 3);
            us* dst = l + (((i << 8) + (wave << 6)) << 3);
            GLDS16(src, dst);
        }
    };

    for (int kk = 0; kk < K; kk += 64) {
        stage(pA, ldsA, m0, kk);
        stage(pB, ldsB, n0, kk);
        __syncthreads();

#pragma unroll
        for (int ks = 0; ks < 4; ks++) {   // k-slot of 16
            short8 af[2], bf[2];
#pragma unroll
            for (int f = 0; f < 2; f++) {
                int ra = (wr << 6) + (f << 5) + l31;
                af[f] = *(const short8*)(
                    &ldsA[(ra << 6) + ((((ks << 1) | l5) ^ (ra & 7)) << 3)]);
                int rb = (wc << 6) + (f << 5) + l31;
                bf[f] = *(const short8*)(
                    &ldsB[(rb << 6) + ((((ks << 1) | l5) ^ (rb & 7)) << 3)]);
            }
#pragma unroll
            for (int fm = 0; fm < 2; fm++)
#pragma unroll
                for (int fn = 0; fn < 2; fn++)
                    acc[fm][fn] = __builtin_amdgcn_mfma_f32_32x32x16_f16(
                        __builtin_bit_cast(half8, af[fm]), __builtin_bit_cast(half8, bf[fn]),
                        acc[fm][fn], 0, 0, 0);
        }
        __syncthreads();
    }

    float bv[2];
#pragma unroll
    for (int fn = 0; fn < 2; fn++)
        bv[fn] = bias ? bias[n0 + (wc << 6) + (fn << 5) + l31] : 0.f;

#pragma unroll
    for (int fm = 0; fm < 2; fm++) {
        int rbase = m0 + (wr << 6) + (fm << 5) + (l5 << 2);
#pragma unroll
        for (int fn = 0; fn < 2; fn++) {
            int col = n0 + (wc << 6) + (fn << 5) + l31;
#pragma unroll
            for (int r = 0; r < 16; r++) {
                float x = acc[fm][fn][r] + bv[fn];
                if (GELU_ACT) x = fast_gelu(x);
                size_t row = (size_t)(rbase + (r & 3) + ((r >> 2) << 3));
                size_t o = zC + row * N + col;
                if (OUT_MODE == 0) ((float*)C)[o] = x;
                else               ((_Float16*)C)[o] = (_Float16)x;
            }
        }
    }
}

extern "C" void kernel_launch(void* const* d_in, const int* in_sizes, int n_in,
                              void* d_out, int out_size, void* d_ws, size_t ws_size,
                              hipStream_t stream) {
    (void)in_sizes; (void)n_in; (void)out_size;
    const float* g_q   = (const float*)d_in[0];
    const float* g_kv  = (const float*)d_in[1];
    const float* g_Wkv = (const float*)d_in[2];
    const float* g_bkv = (const float*)d_in[3];
    const float* g_Wq  = (const float*)d_in[4];
    const float* g_bq  = (const float*)d_in[5];
    const float* g_W1  = (const float*)d_in[6];
    const float* g_b1  = (const float*)d_in[7];
    const float* g_W2  = (const float*)d_in[8];
    const float* g_b2  = (const float*)d_in[9];

    const size_t MiB = 1048576ull;
    const long SH = 2048L * 1024;   // per-batch activation elements
    const long SS = 2048L * 2048;   // per-batch score elements
    char* ws = (char*)d_ws;
    dim3 tb32(32, 8);

    if (ws_size < 176 * MiB) {
        k_sentinel<<<1, 64, 0, stream>>>((float*)d_out);
        return;
    }

    // ---- workspace layout (176 MiB) ----
    // [xq/attnout 32][REGION 128: attn {kf 32 | vT 32 | P_all 64}, MLP hidden 128][wreg 16]
    _Float16* xq  = (_Float16*)ws;
    char*     REGION = ws + 32 * MiB;
    _Float16* kf    = (_Float16*)REGION;
    _Float16* vT    = (_Float16*)(REGION + 32 * MiB);
    _Float16* P_all = (_Float16*)(REGION + 64 * MiB);   // 8 x 2048 x 2048 fp16 = 64 MiB
    _Float16* hidden = (_Float16*)REGION;               // 16384 x 4096 fp16 = 128 MiB
    char* wreg = ws + 160 * MiB;
    _Float16* WkvT = (_Float16*)wreg;                   // 4 MiB
    _Float16* WqT  = (_Float16*)(wreg + 4 * MiB);       // 2 MiB
    _Float16* W1T  = (_Float16*)wreg;                   // 8 MiB (overlays, proj weights dead)
    _Float16* W2T  = (_Float16*)(wreg + 8 * MiB);       // 8 MiB

    // d_out (64+ MiB) as scratch: [xkv 32 | ...] during proj, [scores 32 | q_all 32] in attn
    _Float16* xkv      = (_Float16*)d_out;
    float*    scores_c = (float*)d_out;                        // 2-batch fp32 scores, 32 MiB
    _Float16* q_all    = (_Float16*)((char*)d_out + 32 * MiB); // 32 MiB

    // ---- weights + input casts ----
    k_wtransh<<<dim3(64, 32), tb32, 0, stream>>>(g_Wkv, WkvT, 1024, 2048);
    k_wtransh<<<dim3(32, 32), tb32, 0, stream>>>(g_Wq, WqT, 1024, 1024);
    k_cast<<<4096, 256, 0, stream>>>(g_kv, xkv, 4194304);
    k_cast<<<4096, 256, 0, stream>>>(g_q, xq, 4194304);

    // ---- projections (full-width dispatches) ----
    k_gemm64<4, false><<<dim3(128, 8, 1), 256, 0, stream>>>(
        (const us*)xkv, (const us*)WkvT, g_bkv, kf, 1024, 1024, 0, 0, 0);
    k_gemm64<5, false><<<dim3(128, 8, 1), 256, 0, stream>>>(
        (const us*)xkv, (const us*)(WkvT + (size_t)1024 * 1024), g_bkv + 1024, vT,
        1024, 1024, 0, 0, 0);
    k_gemm64<4, false><<<dim3(128, 8, 1), 256, 0, stream>>>(
        (const us*)xq, (const us*)WqT, g_bq, q_all, 1024, 1024, 0, 0, 0);

    // ---- scores + softmax in 4 chunks of 2 batches (scores in d_out lower half) ----
    for (int c = 0; c < 4; ++c) {
        size_t ro = (size_t)c * 4096 * 1024;
        k_gemm64<0, false><<<dim3(16, 16, 2), 256, 0, stream>>>(
            (const us*)(q_all + ro), (const us*)(kf + ro), nullptr, scores_c,
            2048, 1024, SH, SH, SS);
        k_softmax<<<4096, 256, 0, stream>>>(scores_c, P_all + (size_t)c * 2 * SS);
    }

    // ---- PV for ALL batches in one dispatch (1024 blocks); overwrite xq ----
    k_gemm64<4, false><<<dim3(16, 8, 8), 256, 0, stream>>>(
        (const us*)P_all, (const us*)vT, nullptr, xq, 1024, 2048, SS, SH, SH);

    // ---- MLP on k_gemm32 (within-round A/B vs k_gemm64 elsewhere) ----
    k_wtransh<<<dim3(128, 32), tb32, 0, stream>>>(g_W1, W1T, 1024, 4096);
    k_wtransh<<<dim3(32, 128), tb32, 0, stream>>>(g_W2, W2T, 4096, 1024);
    k_gemm32<4, true><<<dim3(128, 32, 1), 256, 0, stream>>>(
        (const us*)xq, (const us*)W1T, g_b1, hidden, 4096, 1024, 0, 0, 0);
    k_gemm32<0, false><<<dim3(128, 8, 1), 256, 0, stream>>>(
        (const us*)hidden, (const us*)W2T, g_b2, d_out, 1024, 4096, 0, 0, 0);
}

// Round 14
// 708.769 us; speedup vs baseline: 1.0716x; 1.0716x over previous
//
#include <hip/hip_runtime.h>
#include <hip/hip_bf16.h>

typedef __attribute__((ext_vector_type(8))) short short8;
typedef __attribute__((ext_vector_type(8))) _Float16 half8;
typedef __attribute__((ext_vector_type(4))) _Float16 half4v;
typedef __attribute__((ext_vector_type(4))) float f32x4;
typedef unsigned short us;

#define GLDS16(G, L) __builtin_amdgcn_global_load_lds( \
    (const __attribute__((address_space(1))) void*)(G), \
    (__attribute__((address_space(3))) void*)(L), 16, 0, 0)

__global__ void k_sentinel(float* p) {
    if (threadIdx.x == 0 && blockIdx.x == 0) p[0] = 12345.0f;
}

// fast exact-GELU: Abramowitz-Stegun 7.1.26 erf (max abs err 1.5e-7) + __expf
__device__ __forceinline__ float fast_gelu(float x) {
    float ax = fabsf(x) * 0.70710678118654752f;      // |x|/sqrt(2)
    float t = __frcp_rn(fmaf(0.3275911f, ax, 1.0f));
    float p = fmaf(1.061405429f, t, -1.453152027f);
    p = fmaf(p, t, 1.421413741f);
    p = fmaf(p, t, -0.284496736f);
    p = fmaf(p, t, 0.254829592f);
    p = p * t * __expf(-ax * ax);                    // 1 - erf(|z|)
    float erfv = __builtin_copysignf(1.0f - p, x);
    return 0.5f * x * (1.0f + erfv);
}

// ---------------- cast fp32 -> fp16 ----------------
__global__ void k_cast(const float* __restrict__ in, _Float16* __restrict__ out, long n4) {
    long i = (long)blockIdx.x * blockDim.x + threadIdx.x;
    long stride = (long)gridDim.x * blockDim.x;
    for (; i < n4; i += stride) {
        float4 v = ((const float4*)in)[i];
        half4v h;
        h[0] = (_Float16)v.x; h[1] = (_Float16)v.y;
        h[2] = (_Float16)v.z; h[3] = (_Float16)v.w;
        ((half4v*)out)[i] = h;
    }
}

// ---------------- weight transpose+cast: f32 [K][N] -> fp16 [N][K] ----------------
__global__ void k_wtransh(const float* __restrict__ in, _Float16* __restrict__ out,
                          int K, int N) {
    __shared__ float tile[32][33];
    int n0 = blockIdx.x * 32, k0 = blockIdx.y * 32;
    int tx = threadIdx.x, ty = threadIdx.y;
#pragma unroll
    for (int r = ty; r < 32; r += 8)
        tile[r][tx] = in[(size_t)(k0 + r) * N + n0 + tx];
    __syncthreads();
#pragma unroll
    for (int r = ty; r < 32; r += 8)
        out[(size_t)(n0 + r) * K + k0 + tx] = (_Float16)tile[tx][r];
}

// ---------------- row softmax: 2048 fp32 -> 2048 fp16, one block per row ----------------
__device__ __forceinline__ float wredmax(float v) {
#pragma unroll
    for (int off = 32; off > 0; off >>= 1) v = fmaxf(v, __shfl_xor(v, off, 64));
    return v;
}
__device__ __forceinline__ float wredsum(float v) {
#pragma unroll
    for (int off = 32; off > 0; off >>= 1) v += __shfl_xor(v, off, 64);
    return v;
}

__global__ __launch_bounds__(256) void k_softmax(const float* __restrict__ S,
                                                 _Float16* __restrict__ P) {
    __shared__ float red[8];
    size_t base = (size_t)blockIdx.x * 2048;
    int t = threadIdx.x;
    float4 a = ((const float4*)(S + base))[2 * t];
    float4 b = ((const float4*)(S + base))[2 * t + 1];
    float v[8] = {a.x, a.y, a.z, a.w, b.x, b.y, b.z, b.w};
    float m = v[0];
#pragma unroll
    for (int j = 1; j < 8; j++) m = fmaxf(m, v[j]);
    m = wredmax(m);
    int wv = t >> 6;
    if ((t & 63) == 0) red[wv] = m;
    __syncthreads();
    m = fmaxf(fmaxf(red[0], red[1]), fmaxf(red[2], red[3]));
    float s = 0.f;
#pragma unroll
    for (int j = 0; j < 8; j++) { v[j] = __expf(v[j] - m); s += v[j]; }
    s = wredsum(s);
    if ((t & 63) == 0) red[4 + wv] = s;
    __syncthreads();
    s = red[4] + red[5] + red[6] + red[7];
    float inv = 1.f / s;
    half4v o0, o1;
#pragma unroll
    for (int j = 0; j < 4; j++) o0[j] = (_Float16)(v[j] * inv);
#pragma unroll
    for (int j = 0; j < 4; j++) o1[j] = (_Float16)(v[4 + j] * inv);
    ((half4v*)(P + base))[2 * t] = o0;
    ((half4v*)(P + base))[2 * t + 1] = o1;
}

// ---------------- 128-tile fp16 GEMM, BK=64 single-buffer (round-8 winner) ----------------
// m97 structure; per K-step: stage 2x(128x64) tiles (8 gload_lds/thread),
// 1 barrier pair, 2 k-slots x 16 MFMA. Swizzle: 16B-chunk ^= (row&7) applied on
// the GLOBAL source (LDS dest linear, rule #21) and on the ds_read addr.
// At ~3 blocks/CU, wave-level TLP (m114) hides the barrier drain; 8 explicit
// schedule/instruction variants (R3/R5/R9/R10/R11/R13) all measured slower.
// 32x32x16 MFMA is structurally 4-way bank-conflicted here (R13: row stride
// 128B = 0 mod 32 banks; 32 rows -> 8 columns; XOR can't fix what banks
// can't see). This is the practical plateau of the 128-tile structure.
// OUT_MODE: 0=f32  4=fp16  5=fp16 transposed per 2048-row batch
template <int OUT_MODE, bool GELU_ACT>
__global__ __launch_bounds__(256, 2) void k_gemm64(
    const us* __restrict__ A, const us* __restrict__ B,
    const float* __restrict__ bias, void* __restrict__ C,
    int N, int K, long sA, long sB, long sC) {
    __shared__ __align__(16) us ldsA[8192];
    __shared__ __align__(16) us ldsB[8192];

    const int tid = threadIdx.x;
    const int wave = tid >> 6, lane = tid & 63;
    const int wr = wave >> 1, wc = wave & 1;
    const int l15 = lane & 15, l4 = lane >> 4;
    const int m0 = blockIdx.x * 128, n0 = blockIdx.y * 128;

    const us* pA = A + (size_t)blockIdx.z * sA;
    const us* pB = B + (size_t)blockIdx.z * sB;
    const size_t zC = (size_t)blockIdx.z * sC;

    f32x4 acc[4][4] = {};

    auto stage = [&](const us* __restrict__ g, us* l, int r0, int kk) {
#pragma unroll
        for (int i = 0; i < 4; i++) {
            int s = (i << 8) + tid;            // 16B slot 0..1023
            int row = s >> 3;                  // 0..127
            int cl = (s & 7) ^ (row & 7);      // pre-swizzled source chunk
            const us* src = g + (size_t)(r0 + row) * K + kk + (cl << 3);
            us* dst = l + (((i << 8) + (wave << 6)) << 3);  // wave-uniform base
            GLDS16(src, dst);
        }
    };

    for (int kk = 0; kk < K; kk += 64) {
        stage(pA, ldsA, m0, kk);
        stage(pB, ldsB, n0, kk);
        __syncthreads();

#pragma unroll
        for (int ks = 0; ks < 2; ks++) {
            short8 af[4], bf[4];
#pragma unroll
            for (int f = 0; f < 4; f++) {
                int ra = (wr << 6) + (f << 4) + l15;
                af[f] = *(const short8*)(
                    &ldsA[(ra << 6) + ((((ks << 2) | l4) ^ (ra & 7)) << 3)]);
                int rb = (wc << 6) + (f << 4) + l15;
                bf[f] = *(const short8*)(
                    &ldsB[(rb << 6) + ((((ks << 2) | l4) ^ (rb & 7)) << 3)]);
            }
#pragma unroll
            for (int fm = 0; fm < 4; fm++)
#pragma unroll
                for (int fn = 0; fn < 4; fn++)
                    acc[fm][fn] = __builtin_amdgcn_mfma_f32_16x16x32_f16(
                        __builtin_bit_cast(half8, af[fm]), __builtin_bit_cast(half8, bf[fn]),
                        acc[fm][fn], 0, 0, 0);
        }
        __syncthreads();
    }

    float bv[4];
#pragma unroll
    for (int fn = 0; fn < 4; fn++)
        bv[fn] = bias ? bias[n0 + (wc << 6) + (fn << 4) + l15] : 0.f;

#pragma unroll
    for (int fm = 0; fm < 4; fm++) {
        int rbase = m0 + (wr << 6) + (fm << 4) + (l4 << 2);
#pragma unroll
        for (int fn = 0; fn < 4; fn++) {
            int col = n0 + (wc << 6) + (fn << 4) + l15;
#pragma unroll
            for (int r = 0; r < 4; r++) {
                float x = acc[fm][fn][r] + bv[fn];
                if (GELU_ACT) x = fast_gelu(x);
                size_t row = (size_t)(rbase + r);
                if (OUT_MODE == 5) {
                    size_t o = ((row >> 11) * (size_t)N + (size_t)col) * 2048 + (row & 2047);
                    ((_Float16*)C)[o] = (_Float16)x;
                } else {
                    size_t o = zC + row * N + col;
                    if (OUT_MODE == 0) ((float*)C)[o] = x;
                    else               ((_Float16*)C)[o] = (_Float16)x;
                }
            }
        }
    }
}

extern "C" void kernel_launch(void* const* d_in, const int* in_sizes, int n_in,
                              void* d_out, int out_size, void* d_ws, size_t ws_size,
                              hipStream_t stream) {
    (void)in_sizes; (void)n_in; (void)out_size;
    const float* g_q   = (const float*)d_in[0];
    const float* g_kv  = (const float*)d_in[1];
    const float* g_Wkv = (const float*)d_in[2];
    const float* g_bkv = (const float*)d_in[3];
    const float* g_Wq  = (const float*)d_in[4];
    const float* g_bq  = (const float*)d_in[5];
    const float* g_W1  = (const float*)d_in[6];
    const float* g_b1  = (const float*)d_in[7];
    const float* g_W2  = (const float*)d_in[8];
    const float* g_b2  = (const float*)d_in[9];

    const size_t MiB = 1048576ull;
    const long SH = 2048L * 1024;   // per-batch activation elements
    const long SS = 2048L * 2048;   // per-batch score elements
    char* ws = (char*)d_ws;
    dim3 tb32(32, 8);

    if (ws_size < 176 * MiB) {
        k_sentinel<<<1, 64, 0, stream>>>((float*)d_out);
        return;
    }

    // ---- workspace layout (176 MiB) ----
    // [xq/attnout 32][REGION 128: attn {kf 32 | vT 32 | P_all 64}, MLP hidden 128][wreg 16]
    _Float16* xq  = (_Float16*)ws;
    char*     REGION = ws + 32 * MiB;
    _Float16* kf    = (_Float16*)REGION;
    _Float16* vT    = (_Float16*)(REGION + 32 * MiB);
    _Float16* P_all = (_Float16*)(REGION + 64 * MiB);   // 8 x 2048 x 2048 fp16 = 64 MiB
    _Float16* hidden = (_Float16*)REGION;               // 16384 x 4096 fp16 = 128 MiB
    char* wreg = ws + 160 * MiB;
    _Float16* WkvT = (_Float16*)wreg;                   // 4 MiB
    _Float16* WqT  = (_Float16*)(wreg + 4 * MiB);       // 2 MiB
    _Float16* W1T  = (_Float16*)wreg;                   // 8 MiB (overlays, proj weights dead)
    _Float16* W2T  = (_Float16*)(wreg + 8 * MiB);       // 8 MiB

    // d_out (64+ MiB) as scratch: [xkv 32 | ...] during proj, [scores 32 | q_all 32] in attn
    _Float16* xkv      = (_Float16*)d_out;
    float*    scores_c = (float*)d_out;                        // 2-batch fp32 scores, 32 MiB
    _Float16* q_all    = (_Float16*)((char*)d_out + 32 * MiB); // 32 MiB

    // ---- weights + input casts ----
    k_wtransh<<<dim3(64, 32), tb32, 0, stream>>>(g_Wkv, WkvT, 1024, 2048);
    k_wtransh<<<dim3(32, 32), tb32, 0, stream>>>(g_Wq, WqT, 1024, 1024);
    k_cast<<<4096, 256, 0, stream>>>(g_kv, xkv, 4194304);
    k_cast<<<4096, 256, 0, stream>>>(g_q, xq, 4194304);

    // ---- projections (full-width dispatches) ----
    k_gemm64<4, false><<<dim3(128, 8, 1), 256, 0, stream>>>(
        (const us*)xkv, (const us*)WkvT, g_bkv, kf, 1024, 1024, 0, 0, 0);
    k_gemm64<5, false><<<dim3(128, 8, 1), 256, 0, stream>>>(
        (const us*)xkv, (const us*)(WkvT + (size_t)1024 * 1024), g_bkv + 1024, vT,
        1024, 1024, 0, 0, 0);
    k_gemm64<4, false><<<dim3(128, 8, 1), 256, 0, stream>>>(
        (const us*)xq, (const us*)WqT, g_bq, q_all, 1024, 1024, 0, 0, 0);

    // ---- scores + softmax in 4 chunks of 2 batches (scores in d_out lower half) ----
    for (int c = 0; c < 4; ++c) {
        size_t ro = (size_t)c * 4096 * 1024;
        k_gemm64<0, false><<<dim3(16, 16, 2), 256, 0, stream>>>(
            (const us*)(q_all + ro), (const us*)(kf + ro), nullptr, scores_c,
            2048, 1024, SH, SH, SS);
        k_softmax<<<4096, 256, 0, stream>>>(scores_c, P_all + (size_t)c * 2 * SS);
    }

    // ---- PV for ALL batches in one dispatch (1024 blocks); overwrite xq ----
    k_gemm64<4, false><<<dim3(16, 8, 8), 256, 0, stream>>>(
        (const us*)P_all, (const us*)vT, nullptr, xq, 1024, 2048, SS, SH, SH);

    // ---- MLP (hidden overlays REGION; kf/vT/P_all dead) ----
    k_wtransh<<<dim3(128, 32), tb32, 0, stream>>>(g_W1, W1T, 1024, 4096);
    k_wtransh<<<dim3(32, 128), tb32, 0, stream>>>(g_W2, W2T, 4096, 1024);
    k_gemm64<4, true><<<dim3(128, 32, 1), 256, 0, stream>>>(
        (const us*)xq, (const us*)W1T, g_b1, hidden, 4096, 1024, 0, 0, 0);
    k_gemm64<0, false><<<dim3(128, 8, 1), 256, 0, stream>>>(
        (const us*)hidden, (const us*)W2T, g_b2, d_out, 1024, 4096, 0, 0, 0);
}